// Round 7
// baseline (161.226 us; speedup 1.0000x reference)
//
#include <hip/hip_runtime.h>
#include <math.h>

#define ICC   196
#define CH    16
#define NPH   12          // 12*16 = 192 staged channels; tail 4 direct
#define RS2   20          // dwords per point-row in tile (multiple of 4 for b128)
#define BLK   256
#define NCELL 195
#define WSTR  24          // dwords per cell in wlds (24 floats, b128-aligned)

#define WAIT_VM(n)  asm volatile("s_waitcnt vmcnt(" #n ")" ::: "memory")
#define WAIT_LGKM0  asm volatile("s_waitcnt lgkmcnt(0)" ::: "memory")
#define SFENCE      __builtin_amdgcn_sched_barrier(0)
#define SBAR        __builtin_amdgcn_s_barrier()

// per-cell weights, all in VGPRs (loaded from LDS):
// q0={w1x0..3} q1={w1x4,w1x5,w1y0,w1y1} q2={w1y2..5}
// q3={b1_0..3} q4={b1_4,b1_5,w2_0,w2_1} q5={w2_2..5} e0=b2
struct WF { float4 q0,q1,q2,q3,q4,q5; float e0; };

__device__ __forceinline__ WF loadWL(const float* wlds, const float* b2lds, int i) {
    WF w;
    const float4* b = reinterpret_cast<const float4*>(wlds + i * WSTR);
    w.q0 = b[0]; w.q1 = b[1]; w.q2 = b[2]; w.q3 = b[3]; w.q4 = b[4]; w.q5 = b[5];
    w.e0 = b2lds[i];
    return w;
}

__device__ __forceinline__ float cellF(float xi, float y, const WF& w) {
    float h0 = fmaxf(fmaf(y, w.q1.z, fmaf(xi, w.q0.x, w.q3.x)), 0.f);
    float h1 = fmaxf(fmaf(y, w.q1.w, fmaf(xi, w.q0.y, w.q3.y)), 0.f);
    float h2 = fmaxf(fmaf(y, w.q2.x, fmaf(xi, w.q0.z, w.q3.z)), 0.f);
    float h3 = fmaxf(fmaf(y, w.q2.y, fmaf(xi, w.q0.w, w.q3.w)), 0.f);
    float h4 = fmaxf(fmaf(y, w.q2.z, fmaf(xi, w.q1.x, w.q4.x)), 0.f);
    float h5 = fmaxf(fmaf(y, w.q2.w, fmaf(xi, w.q1.y, w.q4.y)), 0.f);
    float s0 = fmaf(h0, w.q4.z, fmaf(h1, w.q4.w, w.e0));
    float s1 = fmaf(h2, w.q5.x, h3 * w.q5.y);
    float s2 = fmaf(h4, w.q5.z, h5 * w.q5.w);
    return fmaxf(s0 + (s1 + s2), 0.f);
}

__global__ __launch_bounds__(BLK, 4) void rnn_kernel(
    const float* __restrict__ x,    // [P, 196]
    const float* __restrict__ W1,   // [195, 2, 6]
    const float* __restrict__ b1,   // [195, 6]
    const float* __restrict__ W2,   // [195, 6]
    const float* __restrict__ b2,   // [195]
    const float* __restrict__ Wf1,  // [2, 6]
    const float* __restrict__ bf1,  // [6]
    const float* __restrict__ Wf2,  // [6]
    const float* __restrict__ bf2,  // [1]
    float* __restrict__ out,        // [P]
    int npoints)
{
    __shared__ float wlds[NCELL * WSTR];  // 18720 B, per-cell packed weights
    __shared__ float b2lds[NCELL];        //   780 B
    __shared__ float tile[BLK * RS2];     // 20480 B, [pt][20] x-channels

    const int tid = threadIdx.x;
    const int p0  = blockIdx.x * BLK;
    const int p   = p0 + tid;

    // ---- one-time weight fill (coalesced global, vector chunks) ----
    for (int i = tid; i < NCELL * 3; i += BLK) {          // W1: 3 float4/cell
        int cell = i / 3, part = i - cell * 3;
        float4 v = reinterpret_cast<const float4*>(W1)[i];
        *reinterpret_cast<float4*>(&wlds[cell * WSTR + part * 4]) = v;
    }
    for (int i = tid; i < NCELL * 3; i += BLK) {          // b1: 3 float2/cell
        int cell = i / 3, part = i - cell * 3;
        float2 v = reinterpret_cast<const float2*>(b1)[i];
        *reinterpret_cast<float2*>(&wlds[cell * WSTR + 12 + part * 2]) = v;
    }
    for (int i = tid; i < NCELL * 3; i += BLK) {          // W2: 3 float2/cell
        int cell = i / 3, part = i - cell * 3;
        float2 v = reinterpret_cast<const float2*>(W2)[i];
        *reinterpret_cast<float2*>(&wlds[cell * WSTR + 18 + part * 2]) = v;
    }
    for (int i = tid; i < NCELL; i += BLK) b2lds[i] = b2[i];

    // staging map: thread t, sweep k -> row rl=(t>>2)+64k, chunk cq=4*(t&3)
    // (4 consecutive lanes cover 64B of one row -> coalesced)
    const int rl0 = tid >> 2;
    const int cq  = (tid & 3) * 4;

    float4 rA[4], rB[4];

    // L_0 -> rA, L_1 -> rB, tail (issue order matters for counted waits)
    #pragma unroll
    for (int k = 0; k < 4; ++k) {
        int rl = rl0 + 64 * k;
        int pc = p0 + rl; if (pc >= npoints) pc = npoints - 1;
        rA[k] = *reinterpret_cast<const float4*>(x + (size_t)pc * ICC + 0 * CH + cq);
    }
    #pragma unroll
    for (int k = 0; k < 4; ++k) {
        int rl = rl0 + 64 * k;
        int pc = p0 + rl; if (pc >= npoints) pc = npoints - 1;
        rB[k] = *reinterpret_cast<const float4*>(x + (size_t)pc * ICC + 1 * CH + cq);
    }
    const int pc_self = (p < npoints) ? p : (npoints - 1);
    const float4 tail = *reinterpret_cast<const float4*>(
        x + (size_t)pc_self * ICC + 192);
    SFENCE;

    // write tile_0 from rA (rB+tail = 5 newest may still fly)
    WAIT_VM(5); SFENCE;
    #pragma unroll
    for (int k = 0; k < 4; ++k)
        *reinterpret_cast<float4*>(&tile[(rl0 + 64 * k) * RS2 + cq]) = rA[k];
    WAIT_LGKM0; SFENCE;
    SBAR;                               // tile_0 + weights visible to all

    float y = tile[tid * RS2];          // y0 = channel 0 of own point

    // ---- phase: slurp xi -> barrier -> issue L(c+2), counted-wait L(c+1),
    //      restage -> barrier -> 16-cell all-DS burst ----
    auto phase = [&](int c, float4 (&cur)[4], float4 (&nxt)[4]) {
        float4 xi4[4];
        #pragma unroll
        for (int k = 0; k < 4; ++k)
            xi4[k] = *reinterpret_cast<const float4*>(&tile[tid * RS2 + 4 * k]);
        WAIT_LGKM0; SFENCE;             // xi in regs (everyone must finish reads)
        SBAR;                           // now safe to overwrite tile

        int cc = (c + 2 < NPH) ? (c + 2) : (NPH - 1);   // clamped (uniform count)
        #pragma unroll
        for (int k = 0; k < 4; ++k) {
            int rl = rl0 + 64 * k;
            int pc = p0 + rl; if (pc >= npoints) pc = npoints - 1;
            nxt[k] = *reinterpret_cast<const float4*>(
                x + (size_t)pc * ICC + cc * CH + cq);
        }
        SFENCE;
        WAIT_VM(4); SFENCE;             // cur landed; nxt (4 newest) keeps flying
        #pragma unroll
        for (int k = 0; k < 4; ++k)
            *reinterpret_cast<float4*>(&tile[(rl0 + 64 * k) * RS2 + cq]) = cur[k];
        WAIT_LGKM0; SFENCE;
        SBAR;                           // tile(c+1) ready

        const float xi[CH] = { xi4[0].x, xi4[0].y, xi4[0].z, xi4[0].w,
                               xi4[1].x, xi4[1].y, xi4[1].z, xi4[1].w,
                               xi4[2].x, xi4[2].y, xi4[2].z, xi4[2].w,
                               xi4[3].x, xi4[3].y, xi4[3].z, xi4[3].w };

        // burst: 2-slot rotating weight prefetch, all ds_read (in-order,
        // counted lgkmcnt by the compiler), zero SMEM, zero barriers.
        WF wA = loadWL(wlds, b2lds, c * CH + 0);
        WF wB = loadWL(wlds, b2lds, c * CH + 1);
        #pragma unroll
        for (int j = 0; j < CH; j += 2) {
            y = cellF(xi[j], y, wA);
            if (j + 2 < CH) wA = loadWL(wlds, b2lds, c * CH + j + 2);
            y = cellF(xi[j + 1], y, wB);
            if (j + 3 < CH) wB = loadWL(wlds, b2lds, c * CH + j + 3);
        }
    };

    #pragma unroll 1
    for (int c2 = 0; c2 < NPH; c2 += 2) {
        phase(c2,     rB, rA);   // cur=rB holds tile(c2+1); nxt=rA gets L(c2+2)
        phase(c2 + 1, rA, rB);
    }

    // ---- tail: cells 192..194 (weights from LDS), then final sigmoid cell ----
    {
        WF w0 = loadWL(wlds, b2lds, 192);
        WF w1c = loadWL(wlds, b2lds, 193);
        WF w2c = loadWL(wlds, b2lds, 194);
        y = cellF(tail.x, y, w0);
        y = cellF(tail.y, y, w1c);
        y = cellF(tail.z, y, w2c);
    }

    const float xf = tail.w;
    float h0 = fmaxf(fmaf(y, Wf1[6],  fmaf(xf, Wf1[0], bf1[0])), 0.0f);
    float h1 = fmaxf(fmaf(y, Wf1[7],  fmaf(xf, Wf1[1], bf1[1])), 0.0f);
    float h2 = fmaxf(fmaf(y, Wf1[8],  fmaf(xf, Wf1[2], bf1[2])), 0.0f);
    float h3 = fmaxf(fmaf(y, Wf1[9],  fmaf(xf, Wf1[3], bf1[3])), 0.0f);
    float h4 = fmaxf(fmaf(y, Wf1[10], fmaf(xf, Wf1[4], bf1[4])), 0.0f);
    float h5 = fmaxf(fmaf(y, Wf1[11], fmaf(xf, Wf1[5], bf1[5])), 0.0f);
    float s0 = fmaf(h0, Wf2[0], fmaf(h1, Wf2[1], bf2[0]));
    float s1 = fmaf(h2, Wf2[2], h3 * Wf2[3]);
    float s2 = fmaf(h4, Wf2[4], h5 * Wf2[5]);
    float t  = s0 + (s1 + s2);

    if (p < npoints)
        out[p] = 1.0f / (1.0f + __expf(-t));
}

extern "C" void kernel_launch(void* const* d_in, const int* in_sizes, int n_in,
                              void* d_out, int out_size, void* d_ws, size_t ws_size,
                              hipStream_t stream) {
    const float* x   = (const float*)d_in[0];
    const float* W1  = (const float*)d_in[1];
    const float* b1  = (const float*)d_in[2];
    const float* W2  = (const float*)d_in[3];
    const float* b2  = (const float*)d_in[4];
    const float* Wf1 = (const float*)d_in[5];
    const float* bf1 = (const float*)d_in[6];
    const float* Wf2 = (const float*)d_in[7];
    const float* bf2 = (const float*)d_in[8];
    float* out = (float*)d_out;

    const int npoints = out_size;                 // B*N = 262144
    const int grid = (npoints + BLK - 1) / BLK;   // 1024 blocks -> 4/CU
    rnn_kernel<<<grid, BLK, 0, stream>>>(x, W1, b1, W2, b2,
                                         Wf1, bf1, Wf2, bf2, out, npoints);
}

// Round 8
// 157.488 us; speedup vs baseline: 1.0237x; 1.0237x over previous
//
#include <hip/hip_runtime.h>
#include <math.h>

#define ICC 196   // channels per point
#define CH  16    // channels per phase
#define NPH 12    // 12*16 = 192 staged channels; tail 4 direct
#define RS2 20    // dwords per point-row in tile (x4 = 80B, b128-aligned)
#define BLK 256   // threads per block == points per block

#define PINV(v)  asm volatile("" : "+v"(v))
#define PINS(v)  asm volatile("" : "+s"(v))
#define WAIT_VM4 asm volatile("s_waitcnt vmcnt(4)" ::: "memory")
#define WAIT_VM0 asm volatile("s_waitcnt vmcnt(0)" ::: "memory")
#define WAIT_LG0 asm volatile("s_waitcnt lgkmcnt(0)" ::: "memory")
#define SFENCE   __builtin_amdgcn_sched_barrier(0)
#define SBAR     __builtin_amdgcn_s_barrier()

// one cell's weights in named scalar fields (wave-uniform -> SGPRs)
struct Wc {
    float a0,a1,a2,a3,a4,a5,a6,a7,a8,a9,a10,a11;  // W1 [2][6] row-major
    float c0,c1,c2,c3,c4,c5;                       // b1
    float d0,d1,d2,d3,d4,d5;                       // W2
    float e0;                                      // b2
};

__device__ __forceinline__ Wc loadW(int i,
    const float* __restrict__ W1, const float* __restrict__ b1,
    const float* __restrict__ W2, const float* __restrict__ b2)
{
    Wc w;
    const float* p = W1 + i * 12;
    w.a0=p[0]; w.a1=p[1]; w.a2=p[2];  w.a3=p[3];  w.a4=p[4];  w.a5=p[5];
    w.a6=p[6]; w.a7=p[7]; w.a8=p[8];  w.a9=p[9];  w.a10=p[10]; w.a11=p[11];
    const float* q = b1 + i * 6;
    w.c0=q[0]; w.c1=q[1]; w.c2=q[2]; w.c3=q[3]; w.c4=q[4]; w.c5=q[5];
    const float* r = W2 + i * 6;
    w.d0=r[0]; w.d1=r[1]; w.d2=r[2]; w.d3=r[3]; w.d4=r[4]; w.d5=r[5];
    w.e0 = b2[i];
    return w;
}

__device__ __forceinline__ void pinW(Wc& w) {
    PINS(w.a0); PINS(w.a1); PINS(w.a2);  PINS(w.a3);  PINS(w.a4);  PINS(w.a5);
    PINS(w.a6); PINS(w.a7); PINS(w.a8);  PINS(w.a9);  PINS(w.a10); PINS(w.a11);
    PINS(w.c0); PINS(w.c1); PINS(w.c2);  PINS(w.c3);  PINS(w.c4);  PINS(w.c5);
    PINS(w.d0); PINS(w.d1); PINS(w.d2);  PINS(w.d3);  PINS(w.d4);  PINS(w.d5);
    PINS(w.e0);
}

__device__ __forceinline__ float cellW(float xi, float y, const Wc& w)
{
    float h0 = fmaxf(fmaf(y, w.a6,  fmaf(xi, w.a0, w.c0)), 0.0f);
    float h1 = fmaxf(fmaf(y, w.a7,  fmaf(xi, w.a1, w.c1)), 0.0f);
    float h2 = fmaxf(fmaf(y, w.a8,  fmaf(xi, w.a2, w.c2)), 0.0f);
    float h3 = fmaxf(fmaf(y, w.a9,  fmaf(xi, w.a3, w.c3)), 0.0f);
    float h4 = fmaxf(fmaf(y, w.a10, fmaf(xi, w.a4, w.c4)), 0.0f);
    float h5 = fmaxf(fmaf(y, w.a11, fmaf(xi, w.a5, w.c5)), 0.0f);
    float s0 = fmaf(h0, w.d0, fmaf(h1, w.d1, w.e0));
    float s1 = fmaf(h2, w.d2, h3 * w.d3);
    float s2 = fmaf(h4, w.d4, h5 * w.d5);
    return fmaxf(s0 + (s1 + s2), 0.0f);
}

// One pipeline phase. CC may be runtime; DO_* flags are compile-time literals.
// reads tile[BUF]; issues L(CC+2) into WNXT; counted-waits WCUR (L(CC+1)) and
// writes it to tile[1-BUF]; pure VALU+SMEM 16-cell burst; ONE raw barrier,
// lgkm-only drain -> the WNXT global loads stay in flight across it.
#define RNN_PHASE(CC, BUF, WCUR, WNXT, DO_ISSUE, DO_VM4, DO_WRITE)            \
  {                                                                           \
    const float* tb = &tile[BUF][tid * RS2];                                  \
    float4 xa = *reinterpret_cast<const float4*>(tb + 0);                     \
    float4 xb = *reinterpret_cast<const float4*>(tb + 4);                     \
    float4 xc = *reinterpret_cast<const float4*>(tb + 8);                     \
    float4 xd = *reinterpret_cast<const float4*>(tb + 12);                    \
    Wc wc = loadW((CC) * CH, W1, b1, W2, b2);                                 \
    if (DO_ISSUE) {                                                           \
      WNXT[0] = *reinterpret_cast<const float4*>(bp0 + (size_t)((CC)+2)*CH);  \
      WNXT[1] = *reinterpret_cast<const float4*>(bp1 + (size_t)((CC)+2)*CH);  \
      WNXT[2] = *reinterpret_cast<const float4*>(bp2 + (size_t)((CC)+2)*CH);  \
      WNXT[3] = *reinterpret_cast<const float4*>(bp3 + (size_t)((CC)+2)*CH);  \
    }                                                                         \
    SFENCE;                                                                   \
    if (DO_WRITE) {                                                           \
      if (DO_VM4) { WAIT_VM4; } else { WAIT_VM0; }                            \
      SFENCE;                                                                 \
      float* tw = &tile[1 - (BUF)][rl0 * RS2 + cq];                           \
      *reinterpret_cast<float4*>(tw + 0 * 64 * RS2) = WCUR[0];                \
      *reinterpret_cast<float4*>(tw + 1 * 64 * RS2) = WCUR[1];                \
      *reinterpret_cast<float4*>(tw + 2 * 64 * RS2) = WCUR[2];                \
      *reinterpret_cast<float4*>(tw + 3 * 64 * RS2) = WCUR[3];                \
    }                                                                         \
    float xi[CH] = { xa.x, xa.y, xa.z, xa.w, xb.x, xb.y, xb.z, xb.w,          \
                     xc.x, xc.y, xc.z, xc.w, xd.x, xd.y, xd.z, xd.w };        \
    _Pragma("unroll")                                                         \
    for (int j = 0; j < CH; ++j) PINV(xi[j]);                                 \
    pinW(wc);                                                                 \
    _Pragma("unroll")                                                         \
    for (int j = 0; j < CH; ++j) {                                            \
      Wc wn;                                                                  \
      if (j < CH - 1) wn = loadW((CC) * CH + j + 1, W1, b1, W2, b2);          \
      y = cellW(xi[j], y, wc);                                                \
      if (j < CH - 1) { pinW(wn); wc = wn; }                                  \
    }                                                                         \
    if (DO_WRITE) { WAIT_LG0; SBAR; }                                         \
  }

__global__ __launch_bounds__(BLK, 4) void rnn_kernel(
    const float* __restrict__ x,    // [P, 196]
    const float* __restrict__ W1,   // [195, 2, 6]
    const float* __restrict__ b1,   // [195, 6]
    const float* __restrict__ W2,   // [195, 6]
    const float* __restrict__ b2,   // [195]
    const float* __restrict__ Wf1,  // [2, 6]
    const float* __restrict__ bf1,  // [6]
    const float* __restrict__ Wf2,  // [6]
    const float* __restrict__ bf2,  // [1]
    float* __restrict__ out,        // [P]
    int npoints)
{
    __shared__ float tile[2][BLK * RS2];   // 2 x 20480 B = 40960 B -> 4 blocks/CU

    const int tid = threadIdx.x;
    const int p0  = blockIdx.x * BLK;
    const int p   = p0 + tid;

    // staging map: thread t, sweep k -> row (t>>2)+64k, channels 4*(t&3)..+3
    // (4 consecutive lanes cover a 64B-contiguous run of one row -> coalesced)
    const int rl0 = tid >> 2;
    const int cq  = (tid & 3) * 4;

    int pr0 = p0 + rl0 +   0; if (pr0 >= npoints) pr0 = npoints - 1;
    int pr1 = p0 + rl0 +  64; if (pr1 >= npoints) pr1 = npoints - 1;
    int pr2 = p0 + rl0 + 128; if (pr2 >= npoints) pr2 = npoints - 1;
    int pr3 = p0 + rl0 + 192; if (pr3 >= npoints) pr3 = npoints - 1;
    const float* bp0 = x + (size_t)pr0 * ICC + cq;
    const float* bp1 = x + (size_t)pr1 * ICC + cq;
    const float* bp2 = x + (size_t)pr2 * ICC + cq;
    const float* bp3 = x + (size_t)pr3 * ICC + cq;

    float4 rA[4], rB[4];

    // ---- prologue: issue L0, L1; wait L0 only; write tile[0]; barrier ----
    rA[0] = *reinterpret_cast<const float4*>(bp0);
    rA[1] = *reinterpret_cast<const float4*>(bp1);
    rA[2] = *reinterpret_cast<const float4*>(bp2);
    rA[3] = *reinterpret_cast<const float4*>(bp3);
    rB[0] = *reinterpret_cast<const float4*>(bp0 + CH);
    rB[1] = *reinterpret_cast<const float4*>(bp1 + CH);
    rB[2] = *reinterpret_cast<const float4*>(bp2 + CH);
    rB[3] = *reinterpret_cast<const float4*>(bp3 + CH);
    SFENCE;
    WAIT_VM4; SFENCE;                       // L0 landed; L1 keeps flying
    {
        float* tw = &tile[0][rl0 * RS2 + cq];
        *reinterpret_cast<float4*>(tw + 0 * 64 * RS2) = rA[0];
        *reinterpret_cast<float4*>(tw + 1 * 64 * RS2) = rA[1];
        *reinterpret_cast<float4*>(tw + 2 * 64 * RS2) = rA[2];
        *reinterpret_cast<float4*>(tw + 3 * 64 * RS2) = rA[3];
    }
    WAIT_LG0; SBAR;                         // tile[0] visible; vmcnt NOT drained

    float y = tile[0][tid * RS2];           // y0 = channel 0 of own point

    // ---- phases 0..9 (uniform: issue L(c+2), vmcnt(4)) ----
    #pragma unroll 1
    for (int c2 = 0; c2 < NPH - 2; c2 += 2) {
        RNN_PHASE(c2,     0, rB, rA, 1, 1, 1);
        RNN_PHASE(c2 + 1, 1, rA, rB, 1, 1, 1);
    }
    // ---- phase 10: nothing to issue; drain L11; write; barrier ----
    RNN_PHASE(10, 0, rB, rA, 0, 0, 1);
    // ---- phase 11: last tile; no write, no barrier ----
    RNN_PHASE(11, 1, rA, rB, 0, 0, 0);

    // ---- tail: channels 192..195 of own point (loaded now; frees regs above) ----
    const int pc_self = (p < npoints) ? p : (npoints - 1);
    const float4 tail = *reinterpret_cast<const float4*>(
        x + (size_t)pc_self * ICC + 192);
    {
        Wc w192 = loadW(192, W1, b1, W2, b2);
        Wc w193 = loadW(193, W1, b1, W2, b2);
        Wc w194 = loadW(194, W1, b1, W2, b2);
        y = cellW(tail.x, y, w192);
        y = cellW(tail.y, y, w193);
        y = cellW(tail.z, y, w194);
    }

    const float xf = tail.w;
    float h0 = fmaxf(fmaf(y, Wf1[6],  fmaf(xf, Wf1[0], bf1[0])), 0.0f);
    float h1 = fmaxf(fmaf(y, Wf1[7],  fmaf(xf, Wf1[1], bf1[1])), 0.0f);
    float h2 = fmaxf(fmaf(y, Wf1[8],  fmaf(xf, Wf1[2], bf1[2])), 0.0f);
    float h3 = fmaxf(fmaf(y, Wf1[9],  fmaf(xf, Wf1[3], bf1[3])), 0.0f);
    float h4 = fmaxf(fmaf(y, Wf1[10], fmaf(xf, Wf1[4], bf1[4])), 0.0f);
    float h5 = fmaxf(fmaf(y, Wf1[11], fmaf(xf, Wf1[5], bf1[5])), 0.0f);
    float s0 = fmaf(h0, Wf2[0], fmaf(h1, Wf2[1], bf2[0]));
    float s1 = fmaf(h2, Wf2[2], h3 * Wf2[3]);
    float s2 = fmaf(h4, Wf2[4], h5 * Wf2[5]);
    float t  = s0 + (s1 + s2);

    if (p < npoints)
        out[p] = 1.0f / (1.0f + __expf(-t));
}

extern "C" void kernel_launch(void* const* d_in, const int* in_sizes, int n_in,
                              void* d_out, int out_size, void* d_ws, size_t ws_size,
                              hipStream_t stream) {
    const float* x   = (const float*)d_in[0];
    const float* W1  = (const float*)d_in[1];
    const float* b1  = (const float*)d_in[2];
    const float* W2  = (const float*)d_in[3];
    const float* b2  = (const float*)d_in[4];
    const float* Wf1 = (const float*)d_in[5];
    const float* bf1 = (const float*)d_in[6];
    const float* Wf2 = (const float*)d_in[7];
    const float* bf2 = (const float*)d_in[8];
    float* out = (float*)d_out;

    const int npoints = out_size;                 // B*N = 262144
    const int grid = (npoints + BLK - 1) / BLK;   // 1024 blocks -> 4/CU
    rnn_kernel<<<grid, BLK, 0, stream>>>(x, W1, b1, W2, b2,
                                         Wf1, bf1, Wf2, bf2, out, npoints);
}

// Round 9
// 152.972 us; speedup vs baseline: 1.0540x; 1.0295x over previous
//
#include <hip/hip_runtime.h>
#include <math.h>

#define ICC 196
#define BLK 256

#define PINS(v)  asm volatile("" : "+s"(v))
#define SFENCE   __builtin_amdgcn_sched_barrier(0)

// one cell's weights in named scalar fields (wave-uniform -> SGPRs)
struct Wc {
    float a0,a1,a2,a3,a4,a5,a6,a7,a8,a9,a10,a11;  // W1 [2][6] row-major
    float c0,c1,c2,c3,c4,c5;                       // b1
    float d0,d1,d2,d3,d4,d5;                       // W2
    float e0;                                      // b2
};

__device__ __forceinline__ Wc loadW(int i,
    const float* __restrict__ W1, const float* __restrict__ b1,
    const float* __restrict__ W2, const float* __restrict__ b2)
{
    Wc w;
    const float* p = W1 + i * 12;
    w.a0=p[0]; w.a1=p[1]; w.a2=p[2];  w.a3=p[3];  w.a4=p[4];  w.a5=p[5];
    w.a6=p[6]; w.a7=p[7]; w.a8=p[8];  w.a9=p[9];  w.a10=p[10]; w.a11=p[11];
    const float* q = b1 + i * 6;
    w.c0=q[0]; w.c1=q[1]; w.c2=q[2]; w.c3=q[3]; w.c4=q[4]; w.c5=q[5];
    const float* r = W2 + i * 6;
    w.d0=r[0]; w.d1=r[1]; w.d2=r[2]; w.d3=r[3]; w.d4=r[4]; w.d5=r[5];
    w.e0 = b2[i];
    return w;
}

__device__ __forceinline__ void pinW(Wc& w) {
    PINS(w.a0); PINS(w.a1); PINS(w.a2);  PINS(w.a3);  PINS(w.a4);  PINS(w.a5);
    PINS(w.a6); PINS(w.a7); PINS(w.a8);  PINS(w.a9);  PINS(w.a10); PINS(w.a11);
    PINS(w.c0); PINS(w.c1); PINS(w.c2);  PINS(w.c3);  PINS(w.c4);  PINS(w.c5);
    PINS(w.d0); PINS(w.d1); PINS(w.d2);  PINS(w.d3);  PINS(w.d4);  PINS(w.d5);
    PINS(w.e0);
}

__device__ __forceinline__ float cellW(float xi, float y, const Wc& w)
{
    float h0 = fmaxf(fmaf(y, w.a6,  fmaf(xi, w.a0, w.c0)), 0.0f);
    float h1 = fmaxf(fmaf(y, w.a7,  fmaf(xi, w.a1, w.c1)), 0.0f);
    float h2 = fmaxf(fmaf(y, w.a8,  fmaf(xi, w.a2, w.c2)), 0.0f);
    float h3 = fmaxf(fmaf(y, w.a9,  fmaf(xi, w.a3, w.c3)), 0.0f);
    float h4 = fmaxf(fmaf(y, w.a10, fmaf(xi, w.a4, w.c4)), 0.0f);
    float h5 = fmaxf(fmaf(y, w.a11, fmaf(xi, w.a5, w.c5)), 0.0f);
    float s0 = fmaf(h0, w.d0, fmaf(h1, w.d1, w.e0));
    float s1 = fmaf(h2, w.d2, h3 * w.d3);
    float s2 = fmaf(h4, w.d4, h5 * w.d5);
    return fmaxf(s0 + (s1 + s2), 0.0f);
}

// 16 cells (base CB) consuming named float4s X0..X3; 1-deep pinned SGPR
// weight pipeline (R5-proven). No arrays, no DS, no memory-clobber asm.
#define BURST16(CB, X0, X1, X2, X3)                                           \
  {                                                                           \
    Wc wc = loadW((CB), W1, b1, W2, b2);                                      \
    pinW(wc);                                                                 \
    Wc wn;                                                                    \
    wn = loadW((CB)+1,  W1,b1,W2,b2); y = cellW(X0.x, y, wc); pinW(wn); wc = wn; \
    wn = loadW((CB)+2,  W1,b1,W2,b2); y = cellW(X0.y, y, wc); pinW(wn); wc = wn; \
    wn = loadW((CB)+3,  W1,b1,W2,b2); y = cellW(X0.z, y, wc); pinW(wn); wc = wn; \
    wn = loadW((CB)+4,  W1,b1,W2,b2); y = cellW(X0.w, y, wc); pinW(wn); wc = wn; \
    wn = loadW((CB)+5,  W1,b1,W2,b2); y = cellW(X1.x, y, wc); pinW(wn); wc = wn; \
    wn = loadW((CB)+6,  W1,b1,W2,b2); y = cellW(X1.y, y, wc); pinW(wn); wc = wn; \
    wn = loadW((CB)+7,  W1,b1,W2,b2); y = cellW(X1.z, y, wc); pinW(wn); wc = wn; \
    wn = loadW((CB)+8,  W1,b1,W2,b2); y = cellW(X1.w, y, wc); pinW(wn); wc = wn; \
    wn = loadW((CB)+9,  W1,b1,W2,b2); y = cellW(X2.x, y, wc); pinW(wn); wc = wn; \
    wn = loadW((CB)+10, W1,b1,W2,b2); y = cellW(X2.y, y, wc); pinW(wn); wc = wn; \
    wn = loadW((CB)+11, W1,b1,W2,b2); y = cellW(X2.z, y, wc); pinW(wn); wc = wn; \
    wn = loadW((CB)+12, W1,b1,W2,b2); y = cellW(X2.w, y, wc); pinW(wn); wc = wn; \
    wn = loadW((CB)+13, W1,b1,W2,b2); y = cellW(X3.x, y, wc); pinW(wn); wc = wn; \
    wn = loadW((CB)+14, W1,b1,W2,b2); y = cellW(X3.y, y, wc); pinW(wn); wc = wn; \
    wn = loadW((CB)+15, W1,b1,W2,b2); y = cellW(X3.z, y, wc); pinW(wn); wc = wn; \
    y = cellW(X3.w, y, wc);                                                   \
  }

__global__ __launch_bounds__(BLK, 4) void rnn_kernel(
    const float* __restrict__ x,    // [P, 196]
    const float* __restrict__ W1,   // [195, 2, 6]
    const float* __restrict__ b1,   // [195, 6]
    const float* __restrict__ W2,   // [195, 6]
    const float* __restrict__ b2,   // [195]
    const float* __restrict__ Wf1,  // [2, 6]
    const float* __restrict__ bf1,  // [6]
    const float* __restrict__ Wf2,  // [6]
    const float* __restrict__ bf2,  // [1]
    float* __restrict__ out,        // [P]
    int npoints)
{
    const int tid = threadIdx.x;
    const int p   = blockIdx.x * BLK + tid;
    const int pc  = (p < npoints) ? p : (npoints - 1);
    // row base: 784*pc bytes -> 16B-aligned (784 % 16 == 0), dwordx4-legal
    const float4* __restrict__ r4 =
        reinterpret_cast<const float4*>(x + (size_t)pc * ICC);

    // double-buffered 64B chunk sets (named regs, NO arrays) + tail
    float4 A0,A1,A2,A3, B0,B1,B2,B3, T;
    A0 = r4[0]; A1 = r4[1]; A2 = r4[2]; A3 = r4[3];   // chunk 0 (ch 0..15)
    B0 = r4[4]; B1 = r4[5]; B2 = r4[6]; B3 = r4[7];   // chunk 1 (ch 16..31)
    T  = r4[48];                                      // ch 192..195
    SFENCE;                                           // loads stay issued here

    float y = A0.x;   // y0 = channel 0 (compiler inserts counted vmcnt)

    // 12 chunks of 16 cells; reload the just-consumed set with chunk c+2.
    // No LDS, no barriers: waves free-run; vmcnt is per-wave and counted
    // by the compiler; a full 16-cell burst (~1000 cyc) covers HBM latency.
    #pragma unroll 1
    for (int c2 = 0; c2 < 12; c2 += 2) {
        BURST16(c2 * 16, A0, A1, A2, A3);
        if (c2 < 10) {                        // reload A <- chunk c2+2
            const float4* q = r4 + (c2 + 2) * 4;
            A0 = q[0]; A1 = q[1]; A2 = q[2]; A3 = q[3];
            SFENCE;
        }
        BURST16(c2 * 16 + 16, B0, B1, B2, B3);
        if (c2 < 10) {                        // reload B <- chunk c2+3
            const float4* q = r4 + (c2 + 3) * 4;
            B0 = q[0]; B1 = q[1]; B2 = q[2]; B3 = q[3];
            SFENCE;
        }
    }

    // tail: cells 192..194, then the final sigmoid cell (channel 195)
    {
        Wc w192 = loadW(192, W1, b1, W2, b2);
        Wc w193 = loadW(193, W1, b1, W2, b2);
        Wc w194 = loadW(194, W1, b1, W2, b2);
        y = cellW(T.x, y, w192);
        y = cellW(T.y, y, w193);
        y = cellW(T.z, y, w194);
    }

    const float xf = T.w;
    float h0 = fmaxf(fmaf(y, Wf1[6],  fmaf(xf, Wf1[0], bf1[0])), 0.0f);
    float h1 = fmaxf(fmaf(y, Wf1[7],  fmaf(xf, Wf1[1], bf1[1])), 0.0f);
    float h2 = fmaxf(fmaf(y, Wf1[8],  fmaf(xf, Wf1[2], bf1[2])), 0.0f);
    float h3 = fmaxf(fmaf(y, Wf1[9],  fmaf(xf, Wf1[3], bf1[3])), 0.0f);
    float h4 = fmaxf(fmaf(y, Wf1[10], fmaf(xf, Wf1[4], bf1[4])), 0.0f);
    float h5 = fmaxf(fmaf(y, Wf1[11], fmaf(xf, Wf1[5], bf1[5])), 0.0f);
    float s0 = fmaf(h0, Wf2[0], fmaf(h1, Wf2[1], bf2[0]));
    float s1 = fmaf(h2, Wf2[2], h3 * Wf2[3]);
    float s2 = fmaf(h4, Wf2[4], h5 * Wf2[5]);
    float t  = s0 + (s1 + s2);

    if (p < npoints)
        out[p] = 1.0f / (1.0f + __expf(-t));
}

extern "C" void kernel_launch(void* const* d_in, const int* in_sizes, int n_in,
                              void* d_out, int out_size, void* d_ws, size_t ws_size,
                              hipStream_t stream) {
    const float* x   = (const float*)d_in[0];
    const float* W1  = (const float*)d_in[1];
    const float* b1  = (const float*)d_in[2];
    const float* W2  = (const float*)d_in[3];
    const float* b2  = (const float*)d_in[4];
    const float* Wf1 = (const float*)d_in[5];
    const float* bf1 = (const float*)d_in[6];
    const float* Wf2 = (const float*)d_in[7];
    const float* bf2 = (const float*)d_in[8];
    float* out = (float*)d_out;

    const int npoints = out_size;                 // B*N = 262144
    const int grid = (npoints + BLK - 1) / BLK;   // 1024 blocks -> 4/CU
    rnn_kernel<<<grid, BLK, 0, stream>>>(x, W1, b1, W2, b2,
                                         Wf1, bf1, Wf2, bf2, out, npoints);
}

// Round 10
// 152.724 us; speedup vs baseline: 1.0557x; 1.0016x over previous
//
#include <hip/hip_runtime.h>
#include <math.h>

#define ICC 196
#define BLK 256

#define SFENCE __builtin_amdgcn_sched_barrier(0)

// One ReLU cell: z=[xi,y] -> Linear(2,6) -> ReLU -> Linear(6,1) -> ReLU.
// Weights referenced directly with a compile-time-constant cell index:
// wave-uniform -> compiler emits s_load + its own software pipeline.
// NO structs, NO pins: keeps SGPR pressure low (R1-proven clean codegen).
__device__ __forceinline__ float cell_step(float xi, float y, int i,
    const float* __restrict__ W1, const float* __restrict__ b1,
    const float* __restrict__ W2, const float* __restrict__ b2)
{
    const float* w1 = W1 + i * 12;   // row0: x-weights, row1: y-weights
    const float* bb = b1 + i * 6;
    const float* w2 = W2 + i * 6;
    float h0 = fmaxf(fmaf(y, w1[6],  fmaf(xi, w1[0], bb[0])), 0.0f);
    float h1 = fmaxf(fmaf(y, w1[7],  fmaf(xi, w1[1], bb[1])), 0.0f);
    float h2 = fmaxf(fmaf(y, w1[8],  fmaf(xi, w1[2], bb[2])), 0.0f);
    float h3 = fmaxf(fmaf(y, w1[9],  fmaf(xi, w1[3], bb[3])), 0.0f);
    float h4 = fmaxf(fmaf(y, w1[10], fmaf(xi, w1[4], bb[4])), 0.0f);
    float h5 = fmaxf(fmaf(y, w1[11], fmaf(xi, w1[5], bb[5])), 0.0f);
    float s0 = fmaf(h0, w2[0], fmaf(h1, w2[1], b2[i]));
    float s1 = fmaf(h2, w2[2], h3 * w2[3]);
    float s2 = fmaf(h4, w2[4], h5 * w2[5]);
    return fmaxf(s0 + (s1 + s2), 0.0f);
}

// 16 cells consuming named float4s X0..X3 (compile-time indices throughout).
#define BURST16(CB, X0, X1, X2, X3)                                 \
  {                                                                 \
    y = cell_step(X0.x, y, (CB)+0,  W1, b1, W2, b2);                \
    y = cell_step(X0.y, y, (CB)+1,  W1, b1, W2, b2);                \
    y = cell_step(X0.z, y, (CB)+2,  W1, b1, W2, b2);                \
    y = cell_step(X0.w, y, (CB)+3,  W1, b1, W2, b2);                \
    y = cell_step(X1.x, y, (CB)+4,  W1, b1, W2, b2);                \
    y = cell_step(X1.y, y, (CB)+5,  W1, b1, W2, b2);                \
    y = cell_step(X1.z, y, (CB)+6,  W1, b1, W2, b2);                \
    y = cell_step(X1.w, y, (CB)+7,  W1, b1, W2, b2);                \
    y = cell_step(X2.x, y, (CB)+8,  W1, b1, W2, b2);                \
    y = cell_step(X2.y, y, (CB)+9,  W1, b1, W2, b2);                \
    y = cell_step(X2.z, y, (CB)+10, W1, b1, W2, b2);                \
    y = cell_step(X2.w, y, (CB)+11, W1, b1, W2, b2);                \
    y = cell_step(X3.x, y, (CB)+12, W1, b1, W2, b2);                \
    y = cell_step(X3.y, y, (CB)+13, W1, b1, W2, b2);                \
    y = cell_step(X3.z, y, (CB)+14, W1, b1, W2, b2);                \
    y = cell_step(X3.w, y, (CB)+15, W1, b1, W2, b2);                \
  }

__global__ __launch_bounds__(BLK, 4) void rnn_kernel(
    const float* __restrict__ x,    // [P, 196]
    const float* __restrict__ W1,   // [195, 2, 6]
    const float* __restrict__ b1,   // [195, 6]
    const float* __restrict__ W2,   // [195, 6]
    const float* __restrict__ b2,   // [195]
    const float* __restrict__ Wf1,  // [2, 6]
    const float* __restrict__ bf1,  // [6]
    const float* __restrict__ Wf2,  // [6]
    const float* __restrict__ bf2,  // [1]
    float* __restrict__ out,        // [P]
    int npoints)
{
    const int tid = threadIdx.x;
    const int p   = blockIdx.x * BLK + tid;
    const int pc  = (p < npoints) ? p : (npoints - 1);
    // row base: 784*pc bytes -> 16B-aligned (784 % 16 == 0), dwordx4-legal
    const float4* __restrict__ r4 =
        reinterpret_cast<const float4*>(x + (size_t)pc * ICC);

    // double-buffered 64B chunk sets (named regs, NO arrays) + tail
    float4 A0,A1,A2,A3, B0,B1,B2,B3, T;
    A0 = r4[0]; A1 = r4[1]; A2 = r4[2]; A3 = r4[3];   // chunk 0 (ch 0..15)
    B0 = r4[4]; B1 = r4[5]; B2 = r4[6]; B3 = r4[7];   // chunk 1 (ch 16..31)
    T  = r4[48];                                      // ch 192..195
    SFENCE;                                           // anchor issue point

    float y = A0.x;   // y0 = channel 0 (compiler inserts counted vmcnt)

    // 12 chunks of 16 cells; reload the just-consumed set with chunk c+2.
    // No LDS, no barriers: waves free-run. The in-flight reload has a full
    // 16-cell burst (~1000+ cyc) of cover before its next use.
    #pragma unroll 1
    for (int c2 = 0; c2 < 12; c2 += 2) {
        BURST16(c2 * 16, A0, A1, A2, A3);
        if (c2 < 10) {                        // reload A <- chunk c2+2
            const float4* q = r4 + (c2 + 2) * 4;
            A0 = q[0]; A1 = q[1]; A2 = q[2]; A3 = q[3];
            SFENCE;
        }
        BURST16(c2 * 16 + 16, B0, B1, B2, B3);
        if (c2 < 10) {                        // reload B <- chunk c2+3
            const float4* q = r4 + (c2 + 3) * 4;
            B0 = q[0]; B1 = q[1]; B2 = q[2]; B3 = q[3];
            SFENCE;
        }
    }

    // tail: cells 192..194, then the final sigmoid cell (channel 195)
    y = cell_step(T.x, y, 192, W1, b1, W2, b2);
    y = cell_step(T.y, y, 193, W1, b1, W2, b2);
    y = cell_step(T.z, y, 194, W1, b1, W2, b2);

    const float xf = T.w;
    float h0 = fmaxf(fmaf(y, Wf1[6],  fmaf(xf, Wf1[0], bf1[0])), 0.0f);
    float h1 = fmaxf(fmaf(y, Wf1[7],  fmaf(xf, Wf1[1], bf1[1])), 0.0f);
    float h2 = fmaxf(fmaf(y, Wf1[8],  fmaf(xf, Wf1[2], bf1[2])), 0.0f);
    float h3 = fmaxf(fmaf(y, Wf1[9],  fmaf(xf, Wf1[3], bf1[3])), 0.0f);
    float h4 = fmaxf(fmaf(y, Wf1[10], fmaf(xf, Wf1[4], bf1[4])), 0.0f);
    float h5 = fmaxf(fmaf(y, Wf1[11], fmaf(xf, Wf1[5], bf1[5])), 0.0f);
    float s0 = fmaf(h0, Wf2[0], fmaf(h1, Wf2[1], bf2[0]));
    float s1 = fmaf(h2, Wf2[2], h3 * Wf2[3]);
    float s2 = fmaf(h4, Wf2[4], h5 * Wf2[5]);
    float t  = s0 + (s1 + s2);

    if (p < npoints)
        out[p] = 1.0f / (1.0f + __expf(-t));
}

extern "C" void kernel_launch(void* const* d_in, const int* in_sizes, int n_in,
                              void* d_out, int out_size, void* d_ws, size_t ws_size,
                              hipStream_t stream) {
    const float* x   = (const float*)d_in[0];
    const float* W1  = (const float*)d_in[1];
    const float* b1  = (const float*)d_in[2];
    const float* W2  = (const float*)d_in[3];
    const float* b2  = (const float*)d_in[4];
    const float* Wf1 = (const float*)d_in[5];
    const float* bf1 = (const float*)d_in[6];
    const float* Wf2 = (const float*)d_in[7];
    const float* bf2 = (const float*)d_in[8];
    float* out = (float*)d_out;

    const int npoints = out_size;                 // B*N = 262144
    const int grid = (npoints + BLK - 1) / BLK;   // 1024 blocks -> 4/CU
    rnn_kernel<<<grid, BLK, 0, stream>>>(x, W1, b1, W2, b2,
                                         Wf1, bf1, Wf2, bf2, out, npoints);
}